// Round 1
// baseline (217.606 us; speedup 1.0000x reference)
//
#include <hip/hip_runtime.h>

#define BTOT 1048576
#define D 17
#define H 8
#define OUT 6
#define E 4
#define G1 64
#define G2 32

__global__ __launch_bounds__(256) void hybrid_ruc_kernel(
    const float* __restrict__ x,
    const float* __restrict__ eW1, const float* __restrict__ eb1,
    const float* __restrict__ eW2, const float* __restrict__ eb2,
    const float* __restrict__ eW3, const float* __restrict__ eb3,
    const float* __restrict__ gW1, const float* __restrict__ gb1,
    const float* __restrict__ gW2, const float* __restrict__ gb2,
    const float* __restrict__ gW3, const float* __restrict__ gb3,
    float* __restrict__ out)
{
    __shared__ float sx[256 * D];
    const int tid = threadIdx.x;
    const long long bbase = (long long)blockIdx.x * 256;

    // ---- stage this block's x rows into LDS (coalesced) ----
    #pragma unroll
    for (int k = 0; k < D; ++k) {
        int t = tid + k * 256;
        sx[t] = x[bbase * D + t];
    }
    __syncthreads();

    // per-thread x row (stride-17 LDS read: 2-way bank alias, free)
    float xr[D];
    #pragma unroll
    for (int i = 0; i < D; ++i) xr[i] = sx[tid * D + i];

    // ---- gating layer1 (17->64) + layer2 (64->32), fused, tiled over j ----
    float h2[G2];
    #pragma unroll
    for (int j = 0; j < G2; ++j) h2[j] = gb2[j];

    #pragma unroll 1
    for (int jt = 0; jt < G1 / 16; ++jt) {      // 4 tiles of 16 hidden units
        float h1t[16];
        #pragma unroll
        for (int c = 0; c < 16; ++c) h1t[c] = gb1[jt * 16 + c];
        #pragma unroll
        for (int i = 0; i < D; ++i) {
            const float xi = xr[i];
            const float* w1row = gW1 + i * G1 + jt * 16;   // uniform addr -> s_load
            #pragma unroll
            for (int c = 0; c < 16; ++c)
                h1t[c] = __builtin_fmaf(xi, w1row[c], h1t[c]);
        }
        #pragma unroll
        for (int c = 0; c < 16; ++c) {
            const float hv = fmaxf(h1t[c], 0.0f);
            const float* w2row = gW2 + (jt * 16 + c) * G2; // uniform addr
            #pragma unroll
            for (int j = 0; j < G2; ++j)
                h2[j] = __builtin_fmaf(hv, w2row[j], h2[j]);
        }
    }

    // ---- gating layer3 (32->4) ----
    float lg[E];
    #pragma unroll
    for (int e = 0; e < E; ++e) lg[e] = gb3[e];
    #pragma unroll
    for (int j = 0; j < G2; ++j) {
        const float hv = fmaxf(h2[j], 0.0f);
        #pragma unroll
        for (int e = 0; e < E; ++e)
            lg[e] = __builtin_fmaf(hv, gW3[j * E + e], lg[e]);
    }

    // ---- argmax, first-max-wins (matches jnp.argmax) ----
    int sel = 0;
    float best = lg[0];
    #pragma unroll
    for (int e = 1; e < E; ++e) {
        if (lg[e] > best) { best = lg[e]; sel = e; }
    }

    // ---- experts: compute all 4 with uniform (scalar) weights, cndmask-select ----
    float pred[OUT];
    #pragma unroll
    for (int o = 0; o < OUT; ++o) pred[o] = 0.0f;

    #pragma unroll 1
    for (int e = 0; e < E; ++e) {
        float t1[H];
        #pragma unroll
        for (int h = 0; h < H; ++h) t1[h] = eb1[e * H + h];
        #pragma unroll
        for (int i = 0; i < D; ++i) {
            const float xi = xr[i];
            const float* w = eW1 + e * D * H + i * H;      // uniform addr
            #pragma unroll
            for (int h = 0; h < H; ++h)
                t1[h] = __builtin_fmaf(xi, w[h], t1[h]);
        }
        float t2[H];
        #pragma unroll
        for (int h = 0; h < H; ++h) t2[h] = eb2[e * H + h];
        #pragma unroll
        for (int k = 0; k < H; ++k) {
            const float tv = fmaxf(t1[k], 0.0f);
            const float* w = eW2 + e * H * H + k * H;      // uniform addr
            #pragma unroll
            for (int h = 0; h < H; ++h)
                t2[h] = __builtin_fmaf(tv, w[h], t2[h]);
        }
        float po[OUT];
        #pragma unroll
        for (int o = 0; o < OUT; ++o) po[o] = eb3[e * OUT + o];
        #pragma unroll
        for (int k = 0; k < H; ++k) {
            const float tv = fmaxf(t2[k], 0.0f);
            const float* w = eW3 + e * H * OUT + k * OUT;  // uniform addr
            #pragma unroll
            for (int o = 0; o < OUT; ++o)
                po[o] = __builtin_fmaf(tv, w[o], po[o]);
        }
        #pragma unroll
        for (int o = 0; o < OUT; ++o)
            pred[o] = (sel == e) ? po[o] : pred[o];        // exactly one e matches
    }

    // ---- store: predictions [B,6] then gating_logits [B,4], flat concat ----
    const long long b = bbase + tid;
    #pragma unroll
    for (int o = 0; o < OUT; ++o) out[b * OUT + o] = pred[o];
    float* lout = out + (long long)BTOT * OUT;
    #pragma unroll
    for (int e = 0; e < E; ++e) lout[b * E + e] = lg[e];
}

extern "C" void kernel_launch(void* const* d_in, const int* in_sizes, int n_in,
                              void* d_out, int out_size, void* d_ws, size_t ws_size,
                              hipStream_t stream) {
    const float* x   = (const float*)d_in[0];
    const float* eW1 = (const float*)d_in[1];
    const float* eb1 = (const float*)d_in[2];
    const float* eW2 = (const float*)d_in[3];
    const float* eb2 = (const float*)d_in[4];
    const float* eW3 = (const float*)d_in[5];
    const float* eb3 = (const float*)d_in[6];
    const float* gW1 = (const float*)d_in[7];
    const float* gb1 = (const float*)d_in[8];
    const float* gW2 = (const float*)d_in[9];
    const float* gb2 = (const float*)d_in[10];
    const float* gW3 = (const float*)d_in[11];
    const float* gb3 = (const float*)d_in[12];
    float* out = (float*)d_out;

    dim3 grid(BTOT / 256), block(256);
    hipLaunchKernelGGL(hybrid_ruc_kernel, grid, block, 0, stream,
                       x, eW1, eb1, eW2, eb2, eW3, eb3,
                       gW1, gb1, gW2, gb2, gW3, gb3, out);
}